// Round 13
// baseline (712.891 us; speedup 1.0000x reference)
//
#include <hip/hip_runtime.h>
#include <cstdint>

#define DEV __device__ __forceinline__

typedef __bf16 bf16x8 __attribute__((ext_vector_type(8)));
typedef float f32x4 __attribute__((ext_vector_type(4)));
typedef unsigned int u32;
typedef unsigned short u16;

DEV u16 f2bf(float f) {
  u32 u = __builtin_bit_cast(u32, f);
  u += 0x7fffu + ((u >> 16) & 1u);
  return (u16)(u >> 16);
}
DEV float bf2f(u16 b) { return __builtin_bit_cast(float, (u32)b << 16); }

// global -> LDS direct DMA, 16B per lane. LDS dest wave-uniform; HW adds lane*16.
DEV void gload16(const u16* g, u16* l) {
  __builtin_amdgcn_global_load_lds(
      (const __attribute__((address_space(1))) u32*)g,
      (__attribute__((address_space(3))) u32*)(uintptr_t)l, 16, 0, 0);
}

// zero the 1-pixel halo of a [8][130][130][256] bf16 buffer; idx < 8*516*32
DEV void border_body(u16* __restrict__ p, int idx) {
  int pix = idx >> 5, c8 = (idx & 31) << 3;
  int b = pix / 516, r = pix % 516;
  int x, y;
  if (r < 130)      { y = 0;   x = r; }
  else if (r < 260) { y = 129; x = r - 130; }
  else if (r < 388) { x = 0;   y = r - 259; }
  else              { x = 129; y = r - 387; }
  u16* dst = p + (((long)b * 130 + y) * 130 + x) * 256 + c8;
  *reinterpret_cast<uint4*>(dst) = uint4{0, 0, 0, 0};
}

// ---------------- x f32 -> bf16 ----------------
__global__ void cvt_f32_bf16(const float* __restrict__ in, u16* __restrict__ out, int n4) {
  int i = blockIdx.x * blockDim.x + threadIdx.x;
  if (i >= n4) return;
  float4 v = reinterpret_cast<const float4*>(in)[i];
  ushort4 o;
  o.x = f2bf(v.x); o.y = f2bf(v.y); o.z = f2bf(v.z); o.w = f2bf(v.w);
  reinterpret_cast<ushort4*>(out)[i] = o;
}

// ---------------- combined prep: weight cvts + conv-weight packs + vpad halo ----------------
// Conv-B layout (cgroup-outer K-order): column r = kt*64 + c_lo, kt = cg*9 + slab,
// slab = ky*3+kx, ic = cg*64 + c_lo.
__global__ void prep(const float* __restrict__ Wq, const float* __restrict__ Wk,
                     const float* __restrict__ Wv, const float* __restrict__ Wc1,
                     const float* __restrict__ Wc2, u16* __restrict__ wqkv,
                     u16* __restrict__ wc1r, u16* __restrict__ wc2r, u16* __restrict__ vpad) {
  const int blk = blockIdx.x, t = threadIdx.x;
  if (blk < 192) {  // Wq|Wk|Wv f32 -> bf16 (16384 float4 each)
    const float* src = blk < 64 ? Wq : (blk < 128 ? Wk : Wv);
    u16* dst = wqkv + (blk < 64 ? 0 : (blk < 128 ? 65536 : 131072));
    const int i = (blk & 63) * 256 + t;
    float4 v = reinterpret_cast<const float4*>(src)[i];
    ushort4 o;
    o.x = f2bf(v.x); o.y = f2bf(v.y); o.z = f2bf(v.z); o.w = f2bf(v.w);
    reinterpret_cast<ushort4*>(dst)[i] = o;
  } else if (blk < 4800) {  // Wc[oc][ic][3][3] -> Bt[oc][(cg*9+slab)*64 + c_lo]
    const int q = blk - 192;
    const float* w = q < 2304 ? Wc1 : Wc2;
    u16* dst = q < 2304 ? wc1r : wc2r;
    const int j = (q % 2304) * 256 + t;
    const int oc = j / 2304, r = j - oc * 2304;
    const int kt = r >> 6, c_lo = r & 63;
    const int cg = kt / 9, slab = kt - cg * 9;
    const int ic = cg * 64 + c_lo;
    dst[j] = f2bf(w[(oc * 256 + ic) * 9 + slab]);
  } else {
    const int idx = (blk - 4800) * 256 + t;
    if (idx < 8 * 516 * 32) border_body(vpad, idx);
  }
}

// ================= 256x256 8-phase GEMM (r10-proven body + PAIRM) =================
// PAIRM=2: one block runs TWO row-adjacent tiles as a continuous virtual K-tile
// sequence (staging rota never drains across the boundary; B(v) period-NKT
// re-stage keeps vmcnt counts exact); acc flushed+zeroed between units.
// STAGE addressing split: per-lane constant base + wave-uniform int offset.
// LDS 128KB dynamic: A[2][256][64] @0, B[2][256][64] @32768 (bf16 elems),
// 16B-slot XOR swizzle (slot ^= row&7) via pre-swizzled global source.
// CONV=0: linear A [M][256]. CONV=1: padded NHWC 3x3 halo, kt=cg*9+slab.
// CONV=2: padded NHWC no shift. SWZ=1: conv image/XCD (PAIRM=1, grid 512).
// SWZ=2: QKV pair (grid 768, 3 col-tiles co-XCD). SWZ=0+PAIRM=2: out_c (grid 256).
// EPI: 0 qkv-split, 1 f32+bias, 2 gelu->bf16 padded. PERB: per-batch B.
template <int CONV, int KTOT, int EPI, int PERB, int SWZ, int PAIRM>
__global__ __launch_bounds__(512, 1) void mm8(
    const u16* __restrict__ A, const u16* __restrict__ Bt,
    const float* __restrict__ bias, void* __restrict__ out,
    u16* __restrict__ vp) {
  extern __shared__ u16 lds[];
  constexpr int NKT = KTOT / 64;
  constexpr int NITER = NKT / 2;
  constexpr int NKT_V = NKT * PAIRM;
  const int tid = threadIdx.x;
  const int wave = tid >> 6, lane = tid & 63;
  const int wr = wave >> 2, wcid = wave & 3;
  const int lrow = lane & 15, lk = lane >> 4;
  int bid = (int)blockIdx.x;
  int tiles[PAIRM];
  int colbase;
  if (SWZ == 1) {  // conv: one image per XCD (PAIRM==1)
    const int xcd = bid & 7, k = bid >> 3;
    tiles[0] = (xcd + ((k >> 5) << 3)) * 32 + (k & 31);
    colbase = 0;
  } else if (SWZ == 2) {  // qkv: pair of row-tiles, 3 col-tiles co-XCD (grid 768)
    const int xcd = bid & 7, s = bid >> 3;     // s in [0,96)
    const int rt2 = s / 3, ct = s - rt2 * 3;   // rt2 in [0,32)
#pragma unroll
    for (int u = 0; u < PAIRM; ++u) tiles[u] = xcd * 64 + rt2 * PAIRM + u;
    colbase = ct * 256;
  } else {  // SWZ==0
    if (PAIRM == 1) {
      tiles[0] = (bid & 7) * 64 + (bid >> 3);
    } else {  // out_c pair (grid 256)
      const int xcd = bid & 7, s = bid >> 3;   // s in [0,32)
#pragma unroll
      for (int u = 0; u < PAIRM; ++u) tiles[u] = xcd * 64 + s * PAIRM + u;
    }
    colbase = 0;
  }
  long rowb[PAIRM];
  int bim[PAIRM], yy0[PAIRM];
#pragma unroll
  for (int u = 0; u < PAIRM; ++u) {
    rowb[u] = (long)tiles[u] * 256;
    bim[u] = tiles[u] >> 6;
    yy0[u] = (tiles[u] & 63) * 2;
  }
  const u16* BT = PERB ? Bt + (long)bim[0] * 65536 : Bt;  // pairs stay in-batch (tiles>>6 equal)

  // per-lane invariant staging bases
  const int rh0 = tid >> 3;
  const int sg0 = (tid & 7) ^ (rh0 & 7);
  const u16* laneA0 = A + rh0 * 256 + sg0 * 8;
  const u16* laneA1 = laneA0 + 64 * 256;
  const u16* laneB0 = BT + (long)rh0 * KTOT + sg0 * 8;
  const u16* laneB1 = laneB0 + (long)64 * KTOT;
  u16* ldsl = lds + wave * 512;

  auto STAGE = [&](int vt, int isB, int half, int bufq) {
    const int kt = (PAIRM > 1) ? (vt & (NKT - 1)) : vt;
    const int un = (PAIRM > 1) ? (vt >> 2) : 0;  // NKT==4 when PAIRM>1
    int uofs;
    if (isB) {
      uofs = (colbase + half * 128) * KTOT + kt * 64;
    } else if (CONV == 1) {
      const int cg = kt / 9;
      const int slab = kt - cg * 9;
      const int ky = slab / 3 - 1, kx = slab - (slab / 3) * 3 - 1;
      uofs = ((bim[0] * 130 + yy0[0] + half + 1 + ky) * 130 + 1 + kx) * 256 + cg * 64;
    } else if (CONV == 2) {
      uofs = ((bim[un] * 130 + yy0[un] + half + 1) * 130 + 1) * 256 + kt * 64;
    } else {
      uofs = (int)(rowb[un] + half * 128) * 256 + kt * 64;
    }
    u16* l = ldsl + (isB ? 32768 : 0) + bufq * 16384 + half * 8192;
    gload16((isB ? laneB0 : laneA0) + uofs, l);
    gload16((isB ? laneB1 : laneA1) + uofs, l + 4096);
  };

  f32x4 acc[8][4] = {};
  bf16x8 bq[4][2];

  const int r0 = (lane >> 4) * 4;
  const int occ = lane & 15;

  // prologue: t0.B0, t0.B1, t0.A0, t0.A1, t1.B0, t1.B1
  STAGE(0, 1, 0, 0); STAGE(0, 1, 1, 0);
  STAGE(0, 0, 0, 0); STAGE(0, 0, 1, 0);
  STAGE(1, 1, 0, 1); STAGE(1, 1, 1, 1);
  asm volatile("s_waitcnt vmcnt(4)" ::: "memory");
  __builtin_amdgcn_s_barrier();
  __builtin_amdgcn_sched_barrier(0);

#pragma unroll
  for (int unit = 0; unit < PAIRM; ++unit) {
    for (int it = 0; it < NITER; ++it) {
      const int u0 = unit * NKT + 2 * it;
#pragma unroll
      for (int ph = 0; ph < 8; ++ph) {
        constexpr int S_ISB[8]  = {0, 0, 1, 1, 0, 0, 1, 1};
        constexpr int S_HALF[8] = {0, 1, 0, 1, 0, 1, 0, 1};
        constexpr int S_BUF[8]  = {1, 1, 0, 0, 0, 0, 1, 1};
        constexpr int S_DT[8]   = {1, 1, 2, 2, 2, 2, 3, 3};
        const int cbuf = ph >> 2, quad = ph & 3;
        if (quad == 0) {  // B frags once per K-tile (8 ds_read_b128)
#pragma unroll
          for (int nf = 0; nf < 4; ++nf)
#pragma unroll
            for (int ks = 0; ks < 2; ++ks) {
              const int n = wcid * 64 + nf * 16 + lrow;
              const int slot = (ks * 4 + lk) ^ (n & 7);
              bq[nf][ks] = *reinterpret_cast<const bf16x8*>(&lds[32768 + cbuf * 16384 + n * 64 + slot * 8]);
            }
        }
        bf16x8 aq[2][2];
#pragma unroll
        for (int mf = 0; mf < 2; ++mf)
#pragma unroll
          for (int ks = 0; ks < 2; ++ks) {
            const int r = wr * 128 + quad * 32 + mf * 16 + lrow;
            const int slot = (ks * 4 + lk) ^ (r & 7);
            aq[mf][ks] = *reinterpret_cast<const bf16x8*>(&lds[cbuf * 16384 + r * 64 + slot * 8]);
          }
        int st = u0 + S_DT[ph];
        if (st > NKT_V - 1) st = NKT_V - 1;  // epilogue dummy stages keep vmcnt exact
        STAGE(st, S_ISB[ph], S_HALF[ph], S_BUF[ph]);
        if (quad == 0)
          asm volatile("s_waitcnt lgkmcnt(8)" ::: "memory");  // early partial drain
        __builtin_amdgcn_s_barrier();
        asm volatile("s_waitcnt lgkmcnt(0)" ::: "memory");
        __builtin_amdgcn_sched_barrier(0);
        __builtin_amdgcn_s_setprio(1);
#pragma unroll
        for (int mf = 0; mf < 2; ++mf)
#pragma unroll
          for (int nf = 0; nf < 4; ++nf)
#pragma unroll
            for (int ks = 0; ks < 2; ++ks)
              acc[quad * 2 + mf][nf] = __builtin_amdgcn_mfma_f32_16x16x32_bf16(
                  aq[mf][ks], bq[nf][ks], acc[quad * 2 + mf][nf], 0, 0, 0);
        __builtin_amdgcn_s_setprio(0);
        __builtin_amdgcn_sched_barrier(0);
        if (quad == 3)
          asm volatile("s_waitcnt vmcnt(4)" ::: "memory");  // counted, never 0
        __builtin_amdgcn_s_barrier();
        __builtin_amdgcn_sched_barrier(0);
      }
    }
    // -------- flush this unit's acc (scalar stores; adjacent lanes coalesce) --------
#pragma unroll
    for (int M = 0; M < 8; ++M) {
#pragma unroll
      for (int nf = 0; nf < 4; ++nf) {
        const int col = wcid * 64 + nf * 16 + occ;
#pragma unroll
        for (int i = 0; i < 4; ++i) {
          const int p = wr * 128 + M * 16 + r0 + i;
          float v = acc[M][nf][i];
          if (EPI == 0) {
            const long rowpix = rowb[unit] + p;
            const int gcol = colbase + col;
            if (gcol < 512) {
              reinterpret_cast<u16*>(out)[rowpix * 512 + gcol] = f2bf(v);
            } else {
              const int b = (int)(rowpix >> 14), rem = (int)(rowpix & 16383);
              vp[(((long)b * 130 + (rem >> 7) + 1) * 130 + (rem & 127) + 1) * 256 + (gcol - 512)] = f2bf(v);
            }
          } else if (EPI == 1) {
            reinterpret_cast<float*>(out)[(rowb[unit] + p) * 256 + col] = v + bias[col];
          } else {
            v += bias[col];
            v = 0.5f * v * (1.0f + erff(v * 0.70710678118654752f));
            const int y = yy0[unit] + (p >> 7), x = p & 127;
            reinterpret_cast<u16*>(out)[(((long)bim[unit] * 130 + y + 1) * 130 + x + 1) * 256 + col] = f2bf(v);
          }
        }
      }
    }
    if (unit + 1 < PAIRM) {
#pragma unroll
      for (int M = 0; M < 8; ++M)
#pragma unroll
        for (int nf = 0; nf < 4; ++nf)
          acc[M][nf] = f32x4{0.f, 0.f, 0.f, 0.f};
    }
  }
}

// ---------------- MFMA gram: G[b,h,d,e] = sum_n k[n,d] q[n,e]  (+ col sumsq) ----------------
__global__ __launch_bounds__(256) void gram_mfma(const u16* __restrict__ qkv,
                                                 float* __restrict__ G,
                                                 float* __restrict__ norm2) {
  __shared__ __align__(16) u16 kT[2][32][40];
  __shared__ __align__(16) u16 qT[2][32][40];
  __shared__ float redq[256][4];
  __shared__ float redk[256][4];
  const int nc = blockIdx.x;
  const int bh = blockIdx.y;
  const int b = bh >> 3, h = bh & 7;
  const int t = threadIdx.x;
  const int wave = t >> 6, lane = t & 63;
  const int mh = wave >> 1, nh = wave & 1;
  const int r = t >> 3, cg = (t & 7) * 4;
  const long n0 = (long)b * 16384 + (long)nc * 4096;
  const u16* qp = qkv + n0 * 512 + h * 32;
  const u16* kp = qp + 256;
  f32x4 acc = {0.f, 0.f, 0.f, 0.f};
  float sq[4] = {0, 0, 0, 0}, sk[4] = {0, 0, 0, 0};

  ushort4 pq[4], pk[4];
#pragma unroll
  for (int j = 0; j < 4; ++j) {
    pq[j] = *reinterpret_cast<const ushort4*>(qp + (long)(j * 32 + r) * 512 + cg);
    pk[j] = *reinterpret_cast<const ushort4*>(kp + (long)(j * 32 + r) * 512 + cg);
  }

  for (int s4 = 0; s4 < 32; ++s4) {
#pragma unroll
    for (int c = 0; c < 4; ++c) {
      const int s = s4 * 4 + c;
      const int buf = s & 1;
      kT[buf][cg + 0][r] = pk[c].x; kT[buf][cg + 1][r] = pk[c].y;
      kT[buf][cg + 2][r] = pk[c].z; kT[buf][cg + 3][r] = pk[c].w;
      qT[buf][cg + 0][r] = pq[c].x; qT[buf][cg + 1][r] = pq[c].y;
      qT[buf][cg + 2][r] = pq[c].z; qT[buf][cg + 3][r] = pq[c].w;
      float f;
      f = bf2f(pq[c].x); sq[0] += f * f;
      f = bf2f(pq[c].y); sq[1] += f * f;
      f = bf2f(pq[c].z); sq[2] += f * f;
      f = bf2f(pq[c].w); sq[3] += f * f;
      f = bf2f(pk[c].x); sk[0] += f * f;
      f = bf2f(pk[c].y); sk[1] += f * f;
      f = bf2f(pk[c].z); sk[2] += f * f;
      f = bf2f(pk[c].w); sk[3] += f * f;
      if (s + 4 < 128) {
        pq[c] = *reinterpret_cast<const ushort4*>(qp + (long)((s + 4) * 32 + r) * 512 + cg);
        pk[c] = *reinterpret_cast<const ushort4*>(kp + (long)((s + 4) * 32 + r) * 512 + cg);
      }
      __syncthreads();
      bf16x8 af = *reinterpret_cast<const bf16x8*>(&kT[buf][mh * 16 + (lane & 15)][(lane >> 4) * 8]);
      bf16x8 bf = *reinterpret_cast<const bf16x8*>(&qT[buf][nh * 16 + (lane & 15)][(lane >> 4) * 8]);
      acc = __builtin_amdgcn_mfma_f32_16x16x32_bf16(af, bf, acc, 0, 0, 0);
    }
  }

  float* gp = G + (long)bh * 1024 + (mh * 16 + (lane >> 4) * 4) * 32 + nh * 16 + (lane & 15);
#pragma unroll
  for (int i = 0; i < 4; ++i) atomicAdd(gp + i * 32, acc[i]);

  __syncthreads();
#pragma unroll
  for (int j = 0; j < 4; ++j) { redq[t][j] = sq[j]; redk[t][j] = sk[j]; }
  __syncthreads();
  if (t < 64) {
    const int qk = t >> 5;
    const int colid = t & 31;
    const int cgi = colid >> 2, j = colid & 3;
    float s = 0.f;
#pragma unroll
    for (int r2 = 0; r2 < 32; ++r2)
      s += qk ? redk[r2 * 8 + cgi][j] : redq[r2 * 8 + cgi][j];
    atomicAdd(&norm2[b * 512 + qk * 256 + h * 32 + colid], s);
  }
}

// ---------------- normalize + rescale + softmax over e ----------------
__global__ void attn_softmax(const float* __restrict__ G, const float* __restrict__ norm2,
                             const float* __restrict__ rescale, float* __restrict__ attn) {
  const int bh = blockIdx.x;
  const int b = bh >> 3, h = bh & 7;
  const int t = threadIdx.x;
  __shared__ float iqs[32], iks[32];
  if (t < 32) {
    iqs[t] = 1.0f / fmaxf(sqrtf(norm2[b * 512 + h * 32 + t]), 1e-12f);
    iks[t] = 1.0f / fmaxf(sqrtf(norm2[b * 512 + 256 + h * 32 + t]), 1e-12f);
  }
  __syncthreads();
  if (t < 32) {
    const float rs = rescale[h];
    const float ikd = iks[t] * rs;
    const float* gp = G + ((long)bh * 32 + t) * 32;
    float l[32];
    float mx = -1e30f;
#pragma unroll
    for (int e = 0; e < 32; ++e) {
      l[e] = gp[e] * ikd * iqs[e];
      mx = fmaxf(mx, l[e]);
    }
    float s = 0.f;
#pragma unroll
    for (int e = 0; e < 32; ++e) {
      l[e] = expf(l[e] - mx);
      s += l[e];
    }
    const float inv = 1.0f / s;
    float* op = attn + ((long)bh * 32 + t) * 32;
#pragma unroll
    for (int e = 0; e < 32; ++e) op[e] = l[e] * inv;
  }
}

// ---------------- weff[b][c][h*32+e] = sum_d Wp[c][h*32+d]*attn[b][h][d][e]; + p1pad halo ----------------
__global__ __launch_bounds__(256) void weff_border(const float* __restrict__ Wp,
                                                   const float* __restrict__ attn,
                                                   u16* __restrict__ weff,
                                                   u16* __restrict__ p1pad) {
  const int blk = blockIdx.x;
  const int t = threadIdx.x;
  if (blk < 64) {
    __shared__ float A[32][33];
    const int b = blk >> 3, h = blk & 7;
    const float* ap = attn + (long)blk * 1024;
    for (int j = t; j < 1024; j += 256) A[j >> 5][j & 31] = ap[j];
    __syncthreads();
    const float* wrow = Wp + (long)t * 256 + h * 32;
    float w[32];
#pragma unroll
    for (int d = 0; d < 32; ++d) w[d] = wrow[d];
    u16* orow = weff + ((long)b * 256 + t) * 256 + h * 32;
#pragma unroll
    for (int e = 0; e < 32; ++e) {
      float s = 0.f;
#pragma unroll
      for (int d = 0; d < 32; ++d) s += w[d] * A[d][e];
      orow[e] = f2bf(s);
    }
  } else {
    const int idx = (blk - 64) * 256 + t;
    if (idx < 8 * 516 * 32) border_body(p1pad, idx);
  }
}

// ---------------- launch ----------------
extern "C" void kernel_launch(void* const* d_in, const int* in_sizes, int n_in,
                              void* d_out, int out_size, void* d_ws, size_t ws_size,
                              hipStream_t stream) {
  const float* x = (const float*)d_in[0];
  const float* Wq = (const float*)d_in[1];
  const float* Wk = (const float*)d_in[2];
  const float* Wv = (const float*)d_in[3];
  const float* resc = (const float*)d_in[4];
  const float* Wp = (const float*)d_in[5];
  const float* bp = (const float*)d_in[6];
  const float* Wc1 = (const float*)d_in[7];
  const float* bc1 = (const float*)d_in[8];
  const float* Wc2 = (const float*)d_in[9];
  const float* bc2 = (const float*)d_in[10];

  char* ws = (char*)d_ws;
  u16* qkv   = (u16*)(ws + 0L);            // [131072][512] q|k ; dead after gram
  u16* p1pad = (u16*)(ws + 0L);            // [8][130][130][256] conv1 out (overlays qkv)
  u16* vpad  = (u16*)(ws + 134217728L);    // [8][130][130][256] v padded
  u16* xb    = (u16*)(ws + 203440128L);    // x bf16
  u16* wqkv  = (u16*)(ws + 270548992L);    // [768][256]
  u16* wc1r  = (u16*)(ws + 270942208L);    // [256][2304]
  u16* wc2r  = (u16*)(ws + 272121856L);    // [256][2304]
  u16* weff  = (u16*)(ws + 273301504L);    // [8][256][256]
  float* norm2 = (float*)(ws + 274350080L);  // [8][512]
  float* G     = (float*)(ws + 274366464L);  // [64][32][32]
  float* attn  = (float*)(ws + 274628608L);  // [64][32][32]

  float* out_c = (float*)d_out;
  float* out_p = out_c + 33554432L;

  hipMemsetAsync(norm2, 0, 16384 + 262144, stream);

  cvt_f32_bf16<<<32768, 256, 0, stream>>>(x, xb, 8388608);
  prep<<<5316, 256, 0, stream>>>(Wq, Wk, Wv, Wc1, Wc2, wqkv, wc1r, wc2r, vpad);

  // QKV projection: paired row-tiles, 3 col-tiles co-XCD (768 blocks, 3 CU-rounds)
  mm8<0, 256, 0, 0, 2, 2><<<768, 512, 131072, stream>>>(xb, wqkv, nullptr, qkv, vpad);

  gram_mfma<<<dim3(4, 64), 256, 0, stream>>>(qkv, G, norm2);
  attn_softmax<<<64, 64, 0, stream>>>(G, norm2, resc, attn);
  weff_border<<<580, 256, 0, stream>>>(Wp, attn, weff, p1pad);

  // out_c = v @ weff[b]^T + bp (paired row-tiles, 256 blocks = 1 CU-round)
  mm8<2, 256, 1, 1, 0, 2><<<256, 512, 131072, stream>>>(vpad, weff, bp, out_c, nullptr);

  // conv branch (round-10 8-phase template, cgroup-outer K-order)
  mm8<1, 2304, 2, 0, 1, 1><<<512, 512, 131072, stream>>>(vpad, wc1r, bc1, p1pad, nullptr);
  mm8<1, 2304, 1, 0, 1, 1><<<512, 512, 131072, stream>>>(p1pad, wc2r, bc2, out_p, nullptr);
}

// Round 14
// 559.947 us; speedup vs baseline: 1.2731x; 1.2731x over previous
//
#include <hip/hip_runtime.h>
#include <cstdint>

#define DEV __device__ __forceinline__

typedef __bf16 bf16x8 __attribute__((ext_vector_type(8)));
typedef float f32x4 __attribute__((ext_vector_type(4)));
typedef unsigned int u32;
typedef unsigned short u16;

DEV u16 f2bf(float f) {
  u32 u = __builtin_bit_cast(u32, f);
  u += 0x7fffu + ((u >> 16) & 1u);
  return (u16)(u >> 16);
}
DEV float bf2f(u16 b) { return __builtin_bit_cast(float, (u32)b << 16); }

// global -> LDS direct DMA, 16B per lane. LDS dest wave-uniform; HW adds lane*16.
DEV void gload16(const u16* g, u16* l) {
  __builtin_amdgcn_global_load_lds(
      (const __attribute__((address_space(1))) u32*)g,
      (__attribute__((address_space(3))) u32*)(uintptr_t)l, 16, 0, 0);
}

// zero the 1-pixel halo of a [8][130][130][256] bf16 buffer; idx < 8*516*32
DEV void border_body(u16* __restrict__ p, int idx) {
  int pix = idx >> 5, c8 = (idx & 31) << 3;
  int b = pix / 516, r = pix % 516;
  int x, y;
  if (r < 130)      { y = 0;   x = r; }
  else if (r < 260) { y = 129; x = r - 130; }
  else if (r < 388) { x = 0;   y = r - 259; }
  else              { x = 129; y = r - 387; }
  u16* dst = p + (((long)b * 130 + y) * 130 + x) * 256 + c8;
  *reinterpret_cast<uint4*>(dst) = uint4{0, 0, 0, 0};
}

// ---------------- x f32 -> bf16 ----------------
__global__ void cvt_f32_bf16(const float* __restrict__ in, u16* __restrict__ out, int n4) {
  int i = blockIdx.x * blockDim.x + threadIdx.x;
  if (i >= n4) return;
  float4 v = reinterpret_cast<const float4*>(in)[i];
  ushort4 o;
  o.x = f2bf(v.x); o.y = f2bf(v.y); o.z = f2bf(v.z); o.w = f2bf(v.w);
  reinterpret_cast<ushort4*>(out)[i] = o;
}

// ---------------- combined prep: weight cvts + conv-weight packs + vpad halo ----------------
// Conv-B layout (cgroup-outer K-order): column r = kt*64 + c_lo, kt = cg*9 + slab,
// slab = ky*3+kx, ic = cg*64 + c_lo.
__global__ void prep(const float* __restrict__ Wq, const float* __restrict__ Wk,
                     const float* __restrict__ Wv, const float* __restrict__ Wc1,
                     const float* __restrict__ Wc2, u16* __restrict__ wqkv,
                     u16* __restrict__ wc1r, u16* __restrict__ wc2r, u16* __restrict__ vpad) {
  const int blk = blockIdx.x, t = threadIdx.x;
  if (blk < 192) {  // Wq|Wk|Wv f32 -> bf16 (16384 float4 each)
    const float* src = blk < 64 ? Wq : (blk < 128 ? Wk : Wv);
    u16* dst = wqkv + (blk < 64 ? 0 : (blk < 128 ? 65536 : 131072));
    const int i = (blk & 63) * 256 + t;
    float4 v = reinterpret_cast<const float4*>(src)[i];
    ushort4 o;
    o.x = f2bf(v.x); o.y = f2bf(v.y); o.z = f2bf(v.z); o.w = f2bf(v.w);
    reinterpret_cast<ushort4*>(dst)[i] = o;
  } else if (blk < 4800) {  // Wc[oc][ic][3][3] -> Bt[oc][(cg*9+slab)*64 + c_lo]
    const int q = blk - 192;
    const float* w = q < 2304 ? Wc1 : Wc2;
    u16* dst = q < 2304 ? wc1r : wc2r;
    const int j = (q % 2304) * 256 + t;
    const int oc = j / 2304, r = j - oc * 2304;
    const int kt = r >> 6, c_lo = r & 63;
    const int cg = kt / 9, slab = kt - cg * 9;
    const int ic = cg * 64 + c_lo;
    dst[j] = f2bf(w[(oc * 256 + ic) * 9 + slab]);
  } else {
    const int idx = (blk - 4800) * 256 + t;
    if (idx < 8 * 516 * 32) border_body(vpad, idx);
  }
}

// ================= 256x256 8-phase GEMM (T2+T3+T4+T5) =================
// r5-proven phase body (early lgkmcnt(8), manual lgkmcnt(0), scalar epilogue).
// STAGE addressing split: per-lane constant base (regs) + wave-uniform int
// offset f(kt,half) on SALU -> ~2 VALU per gload instead of the full 64-bit
// polynomial (+div9/div3 for conv) per lane per phase.
// C tile = A[M,K] * Bt[.,K]^T ; 512 thr = 8 waves (2Mx4N), BK=64.
// LDS 128KB dynamic: A[2][256][64] @0, B[2][256][64] @32768 (bf16 elems),
// 16B-slot XOR swizzle (slot ^= row&7) via pre-swizzled global source.
// CONV=0: linear A [M][256]. CONV=1: padded NHWC, 3x3 halo shifts, K-order
//   kt = cg*9 + slab (channel-group outer) matching prep's conv-B pack.
// CONV=2: padded NHWC, no shift (plain GEMM over vpad).
// SWZ=0: XCD round-robin (grid 512). SWZ=1: conv one-image per XCD.
// SWZ=2: QKV 1536-block: 3 col-tiles of each row-tile co-resident on one XCD.
// EPI: 0 = qkv-split (q,k -> out[.,512]; v -> vp padded), 1 = f32+bias linear,
//      2 = gelu(+bias) -> bf16 padded.   PERB: Bt += bimg*65536 (per-batch weights).
template <int CONV, int KTOT, int EPI, int PERB, int SWZ>
__global__ __launch_bounds__(512, 1) void mm8(
    const u16* __restrict__ A, const u16* __restrict__ Bt,
    const float* __restrict__ bias, void* __restrict__ out,
    u16* __restrict__ vp) {
  extern __shared__ u16 lds[];
  constexpr int NKT = KTOT / 64;
  constexpr int NITER = NKT / 2;
  const int tid = threadIdx.x;
  const int wave = tid >> 6, lane = tid & 63;
  const int wr = wave >> 2, wcid = wave & 3;
  const int lrow = lane & 15, lk = lane >> 4;
  int bid = (int)blockIdx.x;
  int tile, colbase;
  if (SWZ == 1) {
    const int xcd = bid & 7, k = bid >> 3;
    tile = (xcd + ((k >> 5) << 3)) * 32 + (k & 31);
    colbase = 0;
  } else if (SWZ == 2) {
    const int xcd = bid & 7, s = bid >> 3;
    const int r = s / 3;
    tile = xcd * 64 + r;
    colbase = (s - r * 3) * 256;
  } else {
    tile = (bid & 7) * 64 + (bid >> 3);
    colbase = 0;
  }
  const long rowbase = (long)tile * 256;
  const int bimg = tile >> 6;
  const int y0 = (tile & 63) * 2;
  const u16* BT = PERB ? Bt + (long)bimg * 65536 : Bt;

  // per-lane invariant staging bases
  const int rh0 = tid >> 3;
  const int sg0 = (tid & 7) ^ (rh0 & 7);
  const u16* laneA0 = A + rh0 * 256 + sg0 * 8;
  const u16* laneA1 = laneA0 + 64 * 256;
  const u16* laneB0 = BT + (long)rh0 * KTOT + sg0 * 8;
  const u16* laneB1 = laneB0 + (long)64 * KTOT;
  u16* ldsl = lds + wave * 512;

  auto STAGE = [&](int kt, int isB, int half, int bufq) {
    int uofs;
    if (isB) {
      uofs = (colbase + half * 128) * KTOT + kt * 64;
    } else if (CONV == 1) {
      const int cg = kt / 9;
      const int slab = kt - cg * 9;
      const int ky = slab / 3 - 1, kx = slab - (slab / 3) * 3 - 1;
      uofs = ((bimg * 130 + y0 + half + 1 + ky) * 130 + 1 + kx) * 256 + cg * 64;
    } else if (CONV == 2) {
      uofs = ((bimg * 130 + y0 + half + 1) * 130 + 1) * 256 + kt * 64;
    } else {
      uofs = (int)(rowbase + half * 128) * 256 + kt * 64;
    }
    u16* l = ldsl + (isB ? 32768 : 0) + bufq * 16384 + half * 8192;
    gload16((isB ? laneB0 : laneA0) + uofs, l);
    gload16((isB ? laneB1 : laneA1) + uofs, l + 4096);
  };

  f32x4 acc[8][4] = {};
  bf16x8 bq[4][2];

  // prologue: t0.B0, t0.B1, t0.A0, t0.A1, t1.B0, t1.B1
  STAGE(0, 1, 0, 0); STAGE(0, 1, 1, 0);
  STAGE(0, 0, 0, 0); STAGE(0, 0, 1, 0);
  STAGE(1, 1, 0, 1); STAGE(1, 1, 1, 1);
  asm volatile("s_waitcnt vmcnt(4)" ::: "memory");
  __builtin_amdgcn_s_barrier();
  __builtin_amdgcn_sched_barrier(0);

  for (int it = 0; it < NITER; ++it) {
    const int u0 = 2 * it;
#pragma unroll
    for (int ph = 0; ph < 8; ++ph) {
      constexpr int S_ISB[8]  = {0, 0, 1, 1, 0, 0, 1, 1};
      constexpr int S_HALF[8] = {0, 1, 0, 1, 0, 1, 0, 1};
      constexpr int S_BUF[8]  = {1, 1, 0, 0, 0, 0, 1, 1};
      constexpr int S_DT[8]   = {1, 1, 2, 2, 2, 2, 3, 3};
      const int cbuf = ph >> 2, quad = ph & 3;
      if (quad == 0) {  // B frags once per K-tile (8 ds_read_b128)
#pragma unroll
        for (int nf = 0; nf < 4; ++nf)
#pragma unroll
          for (int ks = 0; ks < 2; ++ks) {
            const int n = wcid * 64 + nf * 16 + lrow;
            const int slot = (ks * 4 + lk) ^ (n & 7);
            bq[nf][ks] = *reinterpret_cast<const bf16x8*>(&lds[32768 + cbuf * 16384 + n * 64 + slot * 8]);
          }
      }
      bf16x8 aq[2][2];
#pragma unroll
      for (int mf = 0; mf < 2; ++mf)
#pragma unroll
        for (int ks = 0; ks < 2; ++ks) {
          const int r = wr * 128 + quad * 32 + mf * 16 + lrow;
          const int slot = (ks * 4 + lk) ^ (r & 7);
          aq[mf][ks] = *reinterpret_cast<const bf16x8*>(&lds[cbuf * 16384 + r * 64 + slot * 8]);
        }
      int st = u0 + S_DT[ph];
      if (st > NKT - 1) st = NKT - 1;  // epilogue dummy stages keep vmcnt counts exact
      STAGE(st, S_ISB[ph], S_HALF[ph], S_BUF[ph]);
      if (quad == 0)
        asm volatile("s_waitcnt lgkmcnt(8)" ::: "memory");  // early partial drain (12 reads issued)
      __builtin_amdgcn_s_barrier();
      asm volatile("s_waitcnt lgkmcnt(0)" ::: "memory");
      __builtin_amdgcn_sched_barrier(0);
      __builtin_amdgcn_s_setprio(1);
#pragma unroll
      for (int mf = 0; mf < 2; ++mf)
#pragma unroll
        for (int nf = 0; nf < 4; ++nf)
#pragma unroll
          for (int ks = 0; ks < 2; ++ks)
            acc[quad * 2 + mf][nf] = __builtin_amdgcn_mfma_f32_16x16x32_bf16(
                aq[mf][ks], bq[nf][ks], acc[quad * 2 + mf][nf], 0, 0, 0);
      __builtin_amdgcn_s_setprio(0);
      __builtin_amdgcn_sched_barrier(0);
      if (quad == 3)
        asm volatile("s_waitcnt vmcnt(4)" ::: "memory");  // counted, never 0
      __builtin_amdgcn_s_barrier();
      __builtin_amdgcn_sched_barrier(0);
    }
  }

  // -------- epilogue (scalar stores; adjacent lanes coalesce) --------
  const int r0 = (lane >> 4) * 4;
  const int occ = lane & 15;
#pragma unroll
  for (int M = 0; M < 8; ++M) {
#pragma unroll
    for (int nf = 0; nf < 4; ++nf) {
      const int col = wcid * 64 + nf * 16 + occ;
#pragma unroll
      for (int i = 0; i < 4; ++i) {
        const int p = wr * 128 + M * 16 + r0 + i;
        float v = acc[M][nf][i];
        if (EPI == 0) {
          const long rowpix = rowbase + p;
          const int gcol = colbase + col;
          if (gcol < 512) {
            reinterpret_cast<u16*>(out)[rowpix * 512 + gcol] = f2bf(v);
          } else {
            const int b = (int)(rowpix >> 14), rem = (int)(rowpix & 16383);
            vp[(((long)b * 130 + (rem >> 7) + 1) * 130 + (rem & 127) + 1) * 256 + (gcol - 512)] = f2bf(v);
          }
        } else if (EPI == 1) {
          reinterpret_cast<float*>(out)[(rowbase + p) * 256 + col] = v + bias[col];
        } else {
          v += bias[col];
          v = 0.5f * v * (1.0f + erff(v * 0.70710678118654752f));
          const int y = y0 + (p >> 7), x = p & 127;
          reinterpret_cast<u16*>(out)[(((long)bimg * 130 + y + 1) * 130 + x + 1) * 256 + col] = f2bf(v);
        }
      }
    }
  }
}

// ---------------- MFMA gram: G[b,h,d,e] = sum_n k[n,d] q[n,e]  (+ col sumsq) ----------------
__global__ __launch_bounds__(256) void gram_mfma(const u16* __restrict__ qkv,
                                                 float* __restrict__ G,
                                                 float* __restrict__ norm2) {
  __shared__ __align__(16) u16 kT[2][32][40];
  __shared__ __align__(16) u16 qT[2][32][40];
  __shared__ float redq[256][4];
  __shared__ float redk[256][4];
  const int nc = blockIdx.x;
  const int bh = blockIdx.y;
  const int b = bh >> 3, h = bh & 7;
  const int t = threadIdx.x;
  const int wave = t >> 6, lane = t & 63;
  const int mh = wave >> 1, nh = wave & 1;
  const int r = t >> 3, cg = (t & 7) * 4;
  const long n0 = (long)b * 16384 + (long)nc * 4096;
  const u16* qp = qkv + n0 * 512 + h * 32;
  const u16* kp = qp + 256;
  f32x4 acc = {0.f, 0.f, 0.f, 0.f};
  float sq[4] = {0, 0, 0, 0}, sk[4] = {0, 0, 0, 0};

  ushort4 pq[4], pk[4];
#pragma unroll
  for (int j = 0; j < 4; ++j) {
    pq[j] = *reinterpret_cast<const ushort4*>(qp + (long)(j * 32 + r) * 512 + cg);
    pk[j] = *reinterpret_cast<const ushort4*>(kp + (long)(j * 32 + r) * 512 + cg);
  }

  for (int s4 = 0; s4 < 32; ++s4) {
#pragma unroll
    for (int c = 0; c < 4; ++c) {
      const int s = s4 * 4 + c;
      const int buf = s & 1;
      kT[buf][cg + 0][r] = pk[c].x; kT[buf][cg + 1][r] = pk[c].y;
      kT[buf][cg + 2][r] = pk[c].z; kT[buf][cg + 3][r] = pk[c].w;
      qT[buf][cg + 0][r] = pq[c].x; qT[buf][cg + 1][r] = pq[c].y;
      qT[buf][cg + 2][r] = pq[c].z; qT[buf][cg + 3][r] = pq[c].w;
      float f;
      f = bf2f(pq[c].x); sq[0] += f * f;
      f = bf2f(pq[c].y); sq[1] += f * f;
      f = bf2f(pq[c].z); sq[2] += f * f;
      f = bf2f(pq[c].w); sq[3] += f * f;
      f = bf2f(pk[c].x); sk[0] += f * f;
      f = bf2f(pk[c].y); sk[1] += f * f;
      f = bf2f(pk[c].z); sk[2] += f * f;
      f = bf2f(pk[c].w); sk[3] += f * f;
      if (s + 4 < 128) {
        pq[c] = *reinterpret_cast<const ushort4*>(qp + (long)((s + 4) * 32 + r) * 512 + cg);
        pk[c] = *reinterpret_cast<const ushort4*>(kp + (long)((s + 4) * 32 + r) * 512 + cg);
      }
      __syncthreads();
      bf16x8 af = *reinterpret_cast<const bf16x8*>(&kT[buf][mh * 16 + (lane & 15)][(lane >> 4) * 8]);
      bf16x8 bf = *reinterpret_cast<const bf16x8*>(&qT[buf][nh * 16 + (lane & 15)][(lane >> 4) * 8]);
      acc = __builtin_amdgcn_mfma_f32_16x16x32_bf16(af, bf, acc, 0, 0, 0);
    }
  }

  float* gp = G + (long)bh * 1024 + (mh * 16 + (lane >> 4) * 4) * 32 + nh * 16 + (lane & 15);
#pragma unroll
  for (int i = 0; i < 4; ++i) atomicAdd(gp + i * 32, acc[i]);

  __syncthreads();
#pragma unroll
  for (int j = 0; j < 4; ++j) { redq[t][j] = sq[j]; redk[t][j] = sk[j]; }
  __syncthreads();
  if (t < 64) {
    const int qk = t >> 5;
    const int colid = t & 31;
    const int cgi = colid >> 2, j = colid & 3;
    float s = 0.f;
#pragma unroll
    for (int r2 = 0; r2 < 32; ++r2)
      s += qk ? redk[r2 * 8 + cgi][j] : redq[r2 * 8 + cgi][j];
    atomicAdd(&norm2[b * 512 + qk * 256 + h * 32 + colid], s);
  }
}

// ---------------- normalize + rescale + softmax over e ----------------
__global__ void attn_softmax(const float* __restrict__ G, const float* __restrict__ norm2,
                             const float* __restrict__ rescale, float* __restrict__ attn) {
  const int bh = blockIdx.x;
  const int b = bh >> 3, h = bh & 7;
  const int t = threadIdx.x;
  __shared__ float iqs[32], iks[32];
  if (t < 32) {
    iqs[t] = 1.0f / fmaxf(sqrtf(norm2[b * 512 + h * 32 + t]), 1e-12f);
    iks[t] = 1.0f / fmaxf(sqrtf(norm2[b * 512 + 256 + h * 32 + t]), 1e-12f);
  }
  __syncthreads();
  if (t < 32) {
    const float rs = rescale[h];
    const float ikd = iks[t] * rs;
    const float* gp = G + ((long)bh * 32 + t) * 32;
    float l[32];
    float mx = -1e30f;
#pragma unroll
    for (int e = 0; e < 32; ++e) {
      l[e] = gp[e] * ikd * iqs[e];
      mx = fmaxf(mx, l[e]);
    }
    float s = 0.f;
#pragma unroll
    for (int e = 0; e < 32; ++e) {
      l[e] = expf(l[e] - mx);
      s += l[e];
    }
    const float inv = 1.0f / s;
    float* op = attn + ((long)bh * 32 + t) * 32;
#pragma unroll
    for (int e = 0; e < 32; ++e) op[e] = l[e] * inv;
  }
}

// ---------------- weff[b][c][h*32+e] = sum_d Wp[c][h*32+d]*attn[b][h][d][e]; + p1pad halo ----------------
__global__ __launch_bounds__(256) void weff_border(const float* __restrict__ Wp,
                                                   const float* __restrict__ attn,
                                                   u16* __restrict__ weff,
                                                   u16* __restrict__ p1pad) {
  const int blk = blockIdx.x;
  const int t = threadIdx.x;
  if (blk < 64) {
    __shared__ float A[32][33];
    const int b = blk >> 3, h = blk & 7;
    const float* ap = attn + (long)blk * 1024;
    for (int j = t; j < 1024; j += 256) A[j >> 5][j & 31] = ap[j];
    __syncthreads();
    const float* wrow = Wp + (long)t * 256 + h * 32;
    float w[32];
#pragma unroll
    for (int d = 0; d < 32; ++d) w[d] = wrow[d];
    u16* orow = weff + ((long)b * 256 + t) * 256 + h * 32;
#pragma unroll
    for (int e = 0; e < 32; ++e) {
      float s = 0.f;
#pragma unroll
      for (int d = 0; d < 32; ++d) s += w[d] * A[d][e];
      orow[e] = f2bf(s);
    }
  } else {
    const int idx = (blk - 64) * 256 + t;
    if (idx < 8 * 516 * 32) border_body(p1pad, idx);
  }
}

// ---------------- launch ----------------
extern "C" void kernel_launch(void* const* d_in, const int* in_sizes, int n_in,
                              void* d_out, int out_size, void* d_ws, size_t ws_size,
                              hipStream_t stream) {
  const float* x = (const float*)d_in[0];
  const float* Wq = (const float*)d_in[1];
  const float* Wk = (const float*)d_in[2];
  const float* Wv = (const float*)d_in[3];
  const float* resc = (const float*)d_in[4];
  const float* Wp = (const float*)d_in[5];
  const float* bp = (const float*)d_in[6];
  const float* Wc1 = (const float*)d_in[7];
  const float* bc1 = (const float*)d_in[8];
  const float* Wc2 = (const float*)d_in[9];
  const float* bc2 = (const float*)d_in[10];

  char* ws = (char*)d_ws;
  u16* qkv   = (u16*)(ws + 0L);            // [131072][512] q|k ; dead after gram
  u16* p1pad = (u16*)(ws + 0L);            // [8][130][130][256] conv1 out (overlays qkv)
  u16* vpad  = (u16*)(ws + 134217728L);    // [8][130][130][256] v padded
  u16* xb    = (u16*)(ws + 203440128L);    // x bf16
  u16* wqkv  = (u16*)(ws + 270548992L);    // [768][256]
  u16* wc1r  = (u16*)(ws + 270942208L);    // [256][2304]
  u16* wc2r  = (u16*)(ws + 272121856L);    // [256][2304]
  u16* weff  = (u16*)(ws + 273301504L);    // [8][256][256]
  float* norm2 = (float*)(ws + 274350080L);  // [8][512]
  float* G     = (float*)(ws + 274366464L);  // [64][32][32]
  float* attn  = (float*)(ws + 274628608L);  // [64][32][32]

  float* out_c = (float*)d_out;
  float* out_p = out_c + 33554432L;

  hipMemsetAsync(norm2, 0, 16384 + 262144, stream);

  cvt_f32_bf16<<<32768, 256, 0, stream>>>(x, xb, 8388608);
  prep<<<5316, 256, 0, stream>>>(Wq, Wk, Wv, Wc1, Wc2, wqkv, wc1r, wc2r, vpad);

  // QKV projection: q,k -> qkv[131072][512]; v -> vpad (1536 blocks, co-XCD col-tiles)
  mm8<0, 256, 0, 0, 2><<<1536, 512, 131072, stream>>>(xb, wqkv, nullptr, qkv, vpad);

  gram_mfma<<<dim3(4, 64), 256, 0, stream>>>(qkv, G, norm2);
  attn_softmax<<<64, 64, 0, stream>>>(G, norm2, resc, attn);
  weff_border<<<580, 256, 0, stream>>>(Wp, attn, weff, p1pad);

  // out_c = v @ weff[b]^T + bp   (reads vpad directly)
  mm8<2, 256, 1, 1, 0><<<512, 512, 131072, stream>>>(vpad, weff, bp, out_c, nullptr);

  // conv branch (cgroup-outer K-order for L2 locality)
  mm8<1, 2304, 2, 0, 1><<<512, 512, 131072, stream>>>(vpad, wc1r, bc1, p1pad, nullptr);
  mm8<1, 2304, 1, 0, 1><<<512, 512, 131072, stream>>>(p1pad, wc2r, bc2, out_p, nullptr);
}

// Round 15
// 555.323 us; speedup vs baseline: 1.2837x; 1.0083x over previous
//
#include <hip/hip_runtime.h>
#include <cstdint>

#define DEV __device__ __forceinline__

typedef __bf16 bf16x8 __attribute__((ext_vector_type(8)));
typedef float f32x4 __attribute__((ext_vector_type(4)));
typedef unsigned int u32;
typedef unsigned short u16;

DEV u16 f2bf(float f) {
  u32 u = __builtin_bit_cast(u32, f);
  u += 0x7fffu + ((u >> 16) & 1u);
  return (u16)(u >> 16);
}
DEV float bf2f(u16 b) { return __builtin_bit_cast(float, (u32)b << 16); }

// global -> LDS direct DMA, 16B per lane. LDS dest wave-uniform; HW adds lane*16.
DEV void gload16(const u16* g, u16* l) {
  __builtin_amdgcn_global_load_lds(
      (const __attribute__((address_space(1))) u32*)g,
      (__attribute__((address_space(3))) u32*)(uintptr_t)l, 16, 0, 0);
}

// zero the 1-pixel halo of a [8][130][130][256] bf16 buffer; idx < 8*516*32
DEV void border_body(u16* __restrict__ p, int idx) {
  int pix = idx >> 5, c8 = (idx & 31) << 3;
  int b = pix / 516, r = pix % 516;
  int x, y;
  if (r < 130)      { y = 0;   x = r; }
  else if (r < 260) { y = 129; x = r - 130; }
  else if (r < 388) { x = 0;   y = r - 259; }
  else              { x = 129; y = r - 387; }
  u16* dst = p + (((long)b * 130 + y) * 130 + x) * 256 + c8;
  *reinterpret_cast<uint4*>(dst) = uint4{0, 0, 0, 0};
}

// ---------------- x f32 -> bf16 (grid-stride, 2048 blocks) ----------------
__global__ __launch_bounds__(256) void cvt_f32_bf16(const float* __restrict__ in,
                                                    u16* __restrict__ out, int n4) {
  const int stride = gridDim.x * blockDim.x;
  for (int i = blockIdx.x * blockDim.x + threadIdx.x; i < n4; i += stride) {
    float4 v = reinterpret_cast<const float4*>(in)[i];
    ushort4 o;
    o.x = f2bf(v.x); o.y = f2bf(v.y); o.z = f2bf(v.z); o.w = f2bf(v.w);
    reinterpret_cast<ushort4*>(out)[i] = o;
  }
}

// ---------------- combined prep: weight cvts + conv-weight packs + vpad halo ----------------
// Conv-B layout (cgroup-outer K-order): column r = kt*64 + c_lo, kt = cg*9 + slab,
// slab = ky*3+kx, ic = cg*64 + c_lo.
__global__ void prep(const float* __restrict__ Wq, const float* __restrict__ Wk,
                     const float* __restrict__ Wv, const float* __restrict__ Wc1,
                     const float* __restrict__ Wc2, u16* __restrict__ wqkv,
                     u16* __restrict__ wc1r, u16* __restrict__ wc2r, u16* __restrict__ vpad) {
  const int blk = blockIdx.x, t = threadIdx.x;
  if (blk < 192) {  // Wq|Wk|Wv f32 -> bf16 (16384 float4 each)
    const float* src = blk < 64 ? Wq : (blk < 128 ? Wk : Wv);
    u16* dst = wqkv + (blk < 64 ? 0 : (blk < 128 ? 65536 : 131072));
    const int i = (blk & 63) * 256 + t;
    float4 v = reinterpret_cast<const float4*>(src)[i];
    ushort4 o;
    o.x = f2bf(v.x); o.y = f2bf(v.y); o.z = f2bf(v.z); o.w = f2bf(v.w);
    reinterpret_cast<ushort4*>(dst)[i] = o;
  } else if (blk < 4800) {  // Wc[oc][ic][3][3] -> Bt[oc][(cg*9+slab)*64 + c_lo]
    const int q = blk - 192;
    const float* w = q < 2304 ? Wc1 : Wc2;
    u16* dst = q < 2304 ? wc1r : wc2r;
    const int j = (q % 2304) * 256 + t;
    const int oc = j / 2304, r = j - oc * 2304;
    const int kt = r >> 6, c_lo = r & 63;
    const int cg = kt / 9, slab = kt - cg * 9;
    const int ic = cg * 64 + c_lo;
    dst[j] = f2bf(w[(oc * 256 + ic) * 9 + slab]);
  } else {
    const int idx = (blk - 4800) * 256 + t;
    if (idx < 8 * 516 * 32) border_body(vpad, idx);
  }
}

// ================= 256x256 8-phase GEMM (T2+T3+T4+T5) =================
// r5-proven phase body (early lgkmcnt(8), manual lgkmcnt(0), scalar epilogue).
// STAGE addressing split: per-lane constant base (regs) + wave-uniform int
// offset f(kt,half) on SALU -> ~2 VALU per gload instead of the full 64-bit
// polynomial (+div9/div3 for conv) per lane per phase.
// C tile = A[M,K] * Bt[.,K]^T ; 512 thr = 8 waves (2Mx4N), BK=64.
// LDS 128KB dynamic: A[2][256][64] @0, B[2][256][64] @32768 (bf16 elems),
// 16B-slot XOR swizzle (slot ^= row&7) via pre-swizzled global source.
// CONV=0: linear A [M][256]. CONV=1: padded NHWC, 3x3 halo shifts, K-order
//   kt = cg*9 + slab (channel-group outer) matching prep's conv-B pack.
// CONV=2: padded NHWC, no shift (plain GEMM over vpad).
// SWZ=0: XCD round-robin (grid 512). SWZ=1: conv one-image per XCD.
// SWZ=2: QKV 1536-block: 3 col-tiles of each row-tile co-resident on one XCD.
// EPI: 0 = qkv-split (q,k -> out[.,512]; v -> vp padded), 1 = f32+bias linear,
//      2 = gelu(+bias) -> bf16 padded.   PERB: Bt += bimg*65536 (per-batch weights).
template <int CONV, int KTOT, int EPI, int PERB, int SWZ>
__global__ __launch_bounds__(512, 1) void mm8(
    const u16* __restrict__ A, const u16* __restrict__ Bt,
    const float* __restrict__ bias, void* __restrict__ out,
    u16* __restrict__ vp) {
  extern __shared__ u16 lds[];
  constexpr int NKT = KTOT / 64;
  constexpr int NITER = NKT / 2;
  const int tid = threadIdx.x;
  const int wave = tid >> 6, lane = tid & 63;
  const int wr = wave >> 2, wcid = wave & 3;
  const int lrow = lane & 15, lk = lane >> 4;
  int bid = (int)blockIdx.x;
  int tile, colbase;
  if (SWZ == 1) {
    const int xcd = bid & 7, k = bid >> 3;
    tile = (xcd + ((k >> 5) << 3)) * 32 + (k & 31);
    colbase = 0;
  } else if (SWZ == 2) {
    const int xcd = bid & 7, s = bid >> 3;
    const int r = s / 3;
    tile = xcd * 64 + r;
    colbase = (s - r * 3) * 256;
  } else {
    tile = (bid & 7) * 64 + (bid >> 3);
    colbase = 0;
  }
  const long rowbase = (long)tile * 256;
  const int bimg = tile >> 6;
  const int y0 = (tile & 63) * 2;
  const u16* BT = PERB ? Bt + (long)bimg * 65536 : Bt;

  // per-lane invariant staging bases
  const int rh0 = tid >> 3;
  const int sg0 = (tid & 7) ^ (rh0 & 7);
  const u16* laneA0 = A + rh0 * 256 + sg0 * 8;
  const u16* laneA1 = laneA0 + 64 * 256;
  const u16* laneB0 = BT + (long)rh0 * KTOT + sg0 * 8;
  const u16* laneB1 = laneB0 + (long)64 * KTOT;
  u16* ldsl = lds + wave * 512;

  auto STAGE = [&](int kt, int isB, int half, int bufq) {
    int uofs;
    if (isB) {
      uofs = (colbase + half * 128) * KTOT + kt * 64;
    } else if (CONV == 1) {
      const int cg = kt / 9;
      const int slab = kt - cg * 9;
      const int ky = slab / 3 - 1, kx = slab - (slab / 3) * 3 - 1;
      uofs = ((bimg * 130 + y0 + half + 1 + ky) * 130 + 1 + kx) * 256 + cg * 64;
    } else if (CONV == 2) {
      uofs = ((bimg * 130 + y0 + half + 1) * 130 + 1) * 256 + kt * 64;
    } else {
      uofs = (int)(rowbase + half * 128) * 256 + kt * 64;
    }
    u16* l = ldsl + (isB ? 32768 : 0) + bufq * 16384 + half * 8192;
    gload16((isB ? laneB0 : laneA0) + uofs, l);
    gload16((isB ? laneB1 : laneA1) + uofs, l + 4096);
  };

  f32x4 acc[8][4] = {};
  bf16x8 bq[4][2];

  // prologue: t0.B0, t0.B1, t0.A0, t0.A1, t1.B0, t1.B1
  STAGE(0, 1, 0, 0); STAGE(0, 1, 1, 0);
  STAGE(0, 0, 0, 0); STAGE(0, 0, 1, 0);
  STAGE(1, 1, 0, 1); STAGE(1, 1, 1, 1);
  asm volatile("s_waitcnt vmcnt(4)" ::: "memory");
  __builtin_amdgcn_s_barrier();
  __builtin_amdgcn_sched_barrier(0);

  for (int it = 0; it < NITER; ++it) {
    const int u0 = 2 * it;
#pragma unroll
    for (int ph = 0; ph < 8; ++ph) {
      constexpr int S_ISB[8]  = {0, 0, 1, 1, 0, 0, 1, 1};
      constexpr int S_HALF[8] = {0, 1, 0, 1, 0, 1, 0, 1};
      constexpr int S_BUF[8]  = {1, 1, 0, 0, 0, 0, 1, 1};
      constexpr int S_DT[8]   = {1, 1, 2, 2, 2, 2, 3, 3};
      const int cbuf = ph >> 2, quad = ph & 3;
      if (quad == 0) {  // B frags once per K-tile (8 ds_read_b128)
#pragma unroll
        for (int nf = 0; nf < 4; ++nf)
#pragma unroll
          for (int ks = 0; ks < 2; ++ks) {
            const int n = wcid * 64 + nf * 16 + lrow;
            const int slot = (ks * 4 + lk) ^ (n & 7);
            bq[nf][ks] = *reinterpret_cast<const bf16x8*>(&lds[32768 + cbuf * 16384 + n * 64 + slot * 8]);
          }
      }
      bf16x8 aq[2][2];
#pragma unroll
      for (int mf = 0; mf < 2; ++mf)
#pragma unroll
        for (int ks = 0; ks < 2; ++ks) {
          const int r = wr * 128 + quad * 32 + mf * 16 + lrow;
          const int slot = (ks * 4 + lk) ^ (r & 7);
          aq[mf][ks] = *reinterpret_cast<const bf16x8*>(&lds[cbuf * 16384 + r * 64 + slot * 8]);
        }
      int st = u0 + S_DT[ph];
      if (st > NKT - 1) st = NKT - 1;  // epilogue dummy stages keep vmcnt counts exact
      STAGE(st, S_ISB[ph], S_HALF[ph], S_BUF[ph]);
      if (quad == 0)
        asm volatile("s_waitcnt lgkmcnt(8)" ::: "memory");  // early partial drain (12 reads issued)
      __builtin_amdgcn_s_barrier();
      asm volatile("s_waitcnt lgkmcnt(0)" ::: "memory");
      __builtin_amdgcn_sched_barrier(0);
      __builtin_amdgcn_s_setprio(1);
#pragma unroll
      for (int mf = 0; mf < 2; ++mf)
#pragma unroll
        for (int nf = 0; nf < 4; ++nf)
#pragma unroll
          for (int ks = 0; ks < 2; ++ks)
            acc[quad * 2 + mf][nf] = __builtin_amdgcn_mfma_f32_16x16x32_bf16(
                aq[mf][ks], bq[nf][ks], acc[quad * 2 + mf][nf], 0, 0, 0);
      __builtin_amdgcn_s_setprio(0);
      __builtin_amdgcn_sched_barrier(0);
      if (quad == 3)
        asm volatile("s_waitcnt vmcnt(4)" ::: "memory");  // counted, never 0
      __builtin_amdgcn_s_barrier();
      __builtin_amdgcn_sched_barrier(0);
    }
  }

  // -------- epilogue (scalar stores; adjacent lanes coalesce) --------
  const int r0 = (lane >> 4) * 4;
  const int occ = lane & 15;
#pragma unroll
  for (int M = 0; M < 8; ++M) {
#pragma unroll
    for (int nf = 0; nf < 4; ++nf) {
      const int col = wcid * 64 + nf * 16 + occ;
#pragma unroll
      for (int i = 0; i < 4; ++i) {
        const int p = wr * 128 + M * 16 + r0 + i;
        float v = acc[M][nf][i];
        if (EPI == 0) {
          const long rowpix = rowbase + p;
          const int gcol = colbase + col;
          if (gcol < 512) {
            reinterpret_cast<u16*>(out)[rowpix * 512 + gcol] = f2bf(v);
          } else {
            const int b = (int)(rowpix >> 14), rem = (int)(rowpix & 16383);
            vp[(((long)b * 130 + (rem >> 7) + 1) * 130 + (rem & 127) + 1) * 256 + (gcol - 512)] = f2bf(v);
          }
        } else if (EPI == 1) {
          reinterpret_cast<float*>(out)[(rowbase + p) * 256 + col] = v + bias[col];
        } else {
          v += bias[col];
          v = 0.5f * v * (1.0f + erff(v * 0.70710678118654752f));
          const int y = y0 + (p >> 7), x = p & 127;
          reinterpret_cast<u16*>(out)[(((long)bimg * 130 + y + 1) * 130 + x + 1) * 256 + col] = f2bf(v);
        }
      }
    }
  }
}

// ---------------- MFMA gram: G[b,h,d,e] = sum_n k[n,d] q[n,e]  (+ col sumsq) ----------------
__global__ __launch_bounds__(256) void gram_mfma(const u16* __restrict__ qkv,
                                                 float* __restrict__ G,
                                                 float* __restrict__ norm2) {
  __shared__ __align__(16) u16 kT[2][32][40];
  __shared__ __align__(16) u16 qT[2][32][40];
  __shared__ float redq[256][4];
  __shared__ float redk[256][4];
  const int nc = blockIdx.x;
  const int bh = blockIdx.y;
  const int b = bh >> 3, h = bh & 7;
  const int t = threadIdx.x;
  const int wave = t >> 6, lane = t & 63;
  const int mh = wave >> 1, nh = wave & 1;
  const int r = t >> 3, cg = (t & 7) * 4;
  const long n0 = (long)b * 16384 + (long)nc * 4096;
  const u16* qp = qkv + n0 * 512 + h * 32;
  const u16* kp = qp + 256;
  f32x4 acc = {0.f, 0.f, 0.f, 0.f};
  float sq[4] = {0, 0, 0, 0}, sk[4] = {0, 0, 0, 0};

  ushort4 pq[4], pk[4];
#pragma unroll
  for (int j = 0; j < 4; ++j) {
    pq[j] = *reinterpret_cast<const ushort4*>(qp + (long)(j * 32 + r) * 512 + cg);
    pk[j] = *reinterpret_cast<const ushort4*>(kp + (long)(j * 32 + r) * 512 + cg);
  }

  for (int s4 = 0; s4 < 32; ++s4) {
#pragma unroll
    for (int c = 0; c < 4; ++c) {
      const int s = s4 * 4 + c;
      const int buf = s & 1;
      kT[buf][cg + 0][r] = pk[c].x; kT[buf][cg + 1][r] = pk[c].y;
      kT[buf][cg + 2][r] = pk[c].z; kT[buf][cg + 3][r] = pk[c].w;
      qT[buf][cg + 0][r] = pq[c].x; qT[buf][cg + 1][r] = pq[c].y;
      qT[buf][cg + 2][r] = pq[c].z; qT[buf][cg + 3][r] = pq[c].w;
      float f;
      f = bf2f(pq[c].x); sq[0] += f * f;
      f = bf2f(pq[c].y); sq[1] += f * f;
      f = bf2f(pq[c].z); sq[2] += f * f;
      f = bf2f(pq[c].w); sq[3] += f * f;
      f = bf2f(pk[c].x); sk[0] += f * f;
      f = bf2f(pk[c].y); sk[1] += f * f;
      f = bf2f(pk[c].z); sk[2] += f * f;
      f = bf2f(pk[c].w); sk[3] += f * f;
      if (s + 4 < 128) {
        pq[c] = *reinterpret_cast<const ushort4*>(qp + (long)((s + 4) * 32 + r) * 512 + cg);
        pk[c] = *reinterpret_cast<const ushort4*>(kp + (long)((s + 4) * 32 + r) * 512 + cg);
      }
      __syncthreads();
      bf16x8 af = *reinterpret_cast<const bf16x8*>(&kT[buf][mh * 16 + (lane & 15)][(lane >> 4) * 8]);
      bf16x8 bf = *reinterpret_cast<const bf16x8*>(&qT[buf][nh * 16 + (lane & 15)][(lane >> 4) * 8]);
      acc = __builtin_amdgcn_mfma_f32_16x16x32_bf16(af, bf, acc, 0, 0, 0);
    }
  }

  float* gp = G + (long)bh * 1024 + (mh * 16 + (lane >> 4) * 4) * 32 + nh * 16 + (lane & 15);
#pragma unroll
  for (int i = 0; i < 4; ++i) atomicAdd(gp + i * 32, acc[i]);

  __syncthreads();
#pragma unroll
  for (int j = 0; j < 4; ++j) { redq[t][j] = sq[j]; redk[t][j] = sk[j]; }
  __syncthreads();
  if (t < 64) {
    const int qk = t >> 5;
    const int colid = t & 31;
    const int cgi = colid >> 2, j = colid & 3;
    float s = 0.f;
#pragma unroll
    for (int r2 = 0; r2 < 32; ++r2)
      s += qk ? redk[r2 * 8 + cgi][j] : redq[r2 * 8 + cgi][j];
    atomicAdd(&norm2[b * 512 + qk * 256 + h * 32 + colid], s);
  }
}

// ---------------- normalize + rescale + softmax over e ----------------
__global__ void attn_softmax(const float* __restrict__ G, const float* __restrict__ norm2,
                             const float* __restrict__ rescale, float* __restrict__ attn) {
  const int bh = blockIdx.x;
  const int b = bh >> 3, h = bh & 7;
  const int t = threadIdx.x;
  __shared__ float iqs[32], iks[32];
  if (t < 32) {
    iqs[t] = 1.0f / fmaxf(sqrtf(norm2[b * 512 + h * 32 + t]), 1e-12f);
    iks[t] = 1.0f / fmaxf(sqrtf(norm2[b * 512 + 256 + h * 32 + t]), 1e-12f);
  }
  __syncthreads();
  if (t < 32) {
    const float rs = rescale[h];
    const float ikd = iks[t] * rs;
    const float* gp = G + ((long)bh * 32 + t) * 32;
    float l[32];
    float mx = -1e30f;
#pragma unroll
    for (int e = 0; e < 32; ++e) {
      l[e] = gp[e] * ikd * iqs[e];
      mx = fmaxf(mx, l[e]);
    }
    float s = 0.f;
#pragma unroll
    for (int e = 0; e < 32; ++e) {
      l[e] = expf(l[e] - mx);
      s += l[e];
    }
    const float inv = 1.0f / s;
    float* op = attn + ((long)bh * 32 + t) * 32;
#pragma unroll
    for (int e = 0; e < 32; ++e) op[e] = l[e] * inv;
  }
}

// ---------------- weff[b][c][h*32+e] = sum_d Wp[c][h*32+d]*attn[b][h][d][e]; + p1pad halo ----------------
__global__ __launch_bounds__(256) void weff_border(const float* __restrict__ Wp,
                                                   const float* __restrict__ attn,
                                                   u16* __restrict__ weff,
                                                   u16* __restrict__ p1pad) {
  const int blk = blockIdx.x;
  const int t = threadIdx.x;
  if (blk < 64) {
    __shared__ float A[32][33];
    const int b = blk >> 3, h = blk & 7;
    const float* ap = attn + (long)blk * 1024;
    for (int j = t; j < 1024; j += 256) A[j >> 5][j & 31] = ap[j];
    __syncthreads();
    const float* wrow = Wp + (long)t * 256 + h * 32;
    float w[32];
#pragma unroll
    for (int d = 0; d < 32; ++d) w[d] = wrow[d];
    u16* orow = weff + ((long)b * 256 + t) * 256 + h * 32;
#pragma unroll
    for (int e = 0; e < 32; ++e) {
      float s = 0.f;
#pragma unroll
      for (int d = 0; d < 32; ++d) s += w[d] * A[d][e];
      orow[e] = f2bf(s);
    }
  } else {
    const int idx = (blk - 64) * 256 + t;
    if (idx < 8 * 516 * 32) border_body(p1pad, idx);
  }
}

// ---------------- launch ----------------
extern "C" void kernel_launch(void* const* d_in, const int* in_sizes, int n_in,
                              void* d_out, int out_size, void* d_ws, size_t ws_size,
                              hipStream_t stream) {
  const float* x = (const float*)d_in[0];
  const float* Wq = (const float*)d_in[1];
  const float* Wk = (const float*)d_in[2];
  const float* Wv = (const float*)d_in[3];
  const float* resc = (const float*)d_in[4];
  const float* Wp = (const float*)d_in[5];
  const float* bp = (const float*)d_in[6];
  const float* Wc1 = (const float*)d_in[7];
  const float* bc1 = (const float*)d_in[8];
  const float* Wc2 = (const float*)d_in[9];
  const float* bc2 = (const float*)d_in[10];

  char* ws = (char*)d_ws;
  u16* qkv   = (u16*)(ws + 0L);            // [131072][512] q|k ; dead after gram
  u16* p1pad = (u16*)(ws + 0L);            // [8][130][130][256] conv1 out (overlays qkv)
  u16* vpad  = (u16*)(ws + 134217728L);    // [8][130][130][256] v padded
  u16* xb    = (u16*)(ws + 203440128L);    // x bf16
  u16* wqkv  = (u16*)(ws + 270548992L);    // [768][256]
  u16* wc1r  = (u16*)(ws + 270942208L);    // [256][2304]
  u16* wc2r  = (u16*)(ws + 272121856L);    // [256][2304]
  u16* weff  = (u16*)(ws + 273301504L);    // [8][256][256]
  float* norm2 = (float*)(ws + 274350080L);  // [8][512]
  float* G     = (float*)(ws + 274366464L);  // [64][32][32]
  float* attn  = (float*)(ws + 274628608L);  // [64][32][32]

  float* out_c = (float*)d_out;
  float* out_p = out_c + 33554432L;

  hipMemsetAsync(norm2, 0, 16384 + 262144, stream);

  cvt_f32_bf16<<<2048, 256, 0, stream>>>(x, xb, 8388608);
  prep<<<5316, 256, 0, stream>>>(Wq, Wk, Wv, Wc1, Wc2, wqkv, wc1r, wc2r, vpad);

  // QKV projection: q,k -> qkv[131072][512]; v -> vpad (1536 blocks, co-XCD col-tiles)
  mm8<0, 256, 0, 0, 2><<<1536, 512, 131072, stream>>>(xb, wqkv, nullptr, qkv, vpad);

  gram_mfma<<<dim3(4, 64), 256, 0, stream>>>(qkv, G, norm2);
  attn_softmax<<<64, 64, 0, stream>>>(G, norm2, resc, attn);
  weff_border<<<580, 256, 0, stream>>>(Wp, attn, weff, p1pad);

  // out_c = v @ weff[b]^T + bp   (reads vpad directly)
  mm8<2, 256, 1, 1, 0><<<512, 512, 131072, stream>>>(vpad, weff, bp, out_c, nullptr);

  // conv branch (cgroup-outer K-order for L2 locality)
  mm8<1, 2304, 2, 0, 1><<<512, 512, 131072, stream>>>(vpad, wc1r, bc1, p1pad, nullptr);
  mm8<1, 2304, 1, 0, 1><<<512, 512, 131072, stream>>>(p1pad, wc2r, bc2, out_p, nullptr);
}

// Round 16
// 547.207 us; speedup vs baseline: 1.3028x; 1.0148x over previous
//
#include <hip/hip_runtime.h>
#include <cstdint>

#define DEV __device__ __forceinline__

typedef __bf16 bf16x8 __attribute__((ext_vector_type(8)));
typedef float f32x4 __attribute__((ext_vector_type(4)));
typedef unsigned int u32;
typedef unsigned short u16;

DEV u16 f2bf(float f) {
  u32 u = __builtin_bit_cast(u32, f);
  u += 0x7fffu + ((u >> 16) & 1u);
  return (u16)(u >> 16);
}
DEV float bf2f(u16 b) { return __builtin_bit_cast(float, (u32)b << 16); }

// global -> LDS direct DMA, 16B per lane. LDS dest wave-uniform; HW adds lane*16.
DEV void gload16(const u16* g, u16* l) {
  __builtin_amdgcn_global_load_lds(
      (const __attribute__((address_space(1))) u32*)g,
      (__attribute__((address_space(3))) u32*)(uintptr_t)l, 16, 0, 0);
}

// zero the 1-pixel halo of a [8][130][130][256] bf16 buffer; idx < 8*516*32
DEV void border_body(u16* __restrict__ p, int idx) {
  int pix = idx >> 5, c8 = (idx & 31) << 3;
  int b = pix / 516, r = pix % 516;
  int x, y;
  if (r < 130)      { y = 0;   x = r; }
  else if (r < 260) { y = 129; x = r - 130; }
  else if (r < 388) { x = 0;   y = r - 259; }
  else              { x = 129; y = r - 387; }
  u16* dst = p + (((long)b * 130 + y) * 130 + x) * 256 + c8;
  *reinterpret_cast<uint4*>(dst) = uint4{0, 0, 0, 0};
}

// ---------------- fused prep: x cvt (grid-stride) + weight cvts + conv packs + vpad halo ----------------
// Conv-B layout (cgroup-outer K-order): column r = kt*64 + c_lo, kt = cg*9 + slab,
// slab = ky*3+kx, ic = cg*64 + c_lo.
__global__ __launch_bounds__(256) void prep(
    const float* __restrict__ x, u16* __restrict__ xb,
    const float* __restrict__ Wq, const float* __restrict__ Wk,
    const float* __restrict__ Wv, const float* __restrict__ Wc1,
    const float* __restrict__ Wc2, u16* __restrict__ wqkv,
    u16* __restrict__ wc1r, u16* __restrict__ wc2r, u16* __restrict__ vpad) {
  const int blk = blockIdx.x, t = threadIdx.x;
  if (blk < 2048) {  // x f32 -> bf16, grid-stride over 8388608 float4
    const int stride = 2048 * 256;
    for (int i = blk * 256 + t; i < 8388608; i += stride) {
      float4 v = reinterpret_cast<const float4*>(x)[i];
      ushort4 o;
      o.x = f2bf(v.x); o.y = f2bf(v.y); o.z = f2bf(v.z); o.w = f2bf(v.w);
      reinterpret_cast<ushort4*>(xb)[i] = o;
    }
  } else if (blk < 2240) {  // Wq|Wk|Wv f32 -> bf16 (16384 float4 each)
    const int q = blk - 2048;
    const float* src = q < 64 ? Wq : (q < 128 ? Wk : Wv);
    u16* dst = wqkv + (q < 64 ? 0 : (q < 128 ? 65536 : 131072));
    const int i = (q & 63) * 256 + t;
    float4 v = reinterpret_cast<const float4*>(src)[i];
    ushort4 o;
    o.x = f2bf(v.x); o.y = f2bf(v.y); o.z = f2bf(v.z); o.w = f2bf(v.w);
    reinterpret_cast<ushort4*>(dst)[i] = o;
  } else if (blk < 6848) {  // Wc[oc][ic][3][3] -> Bt[oc][(cg*9+slab)*64 + c_lo]
    const int q = blk - 2240;
    const float* w = q < 2304 ? Wc1 : Wc2;
    u16* dst = q < 2304 ? wc1r : wc2r;
    const int j = (q % 2304) * 256 + t;
    const int oc = j / 2304, r = j - oc * 2304;
    const int kt = r >> 6, c_lo = r & 63;
    const int cg = kt / 9, slab = kt - cg * 9;
    const int ic = cg * 64 + c_lo;
    dst[j] = f2bf(w[(oc * 256 + ic) * 9 + slab]);
  } else {
    const int idx = (blk - 6848) * 256 + t;
    if (idx < 8 * 516 * 32) border_body(vpad, idx);
  }
}

// ================= 256x256 8-phase GEMM (T2+T3+T4+T5) =================
// r5-proven phase body (early lgkmcnt(8), manual lgkmcnt(0), scalar epilogue).
// STAGE addressing split: per-lane constant base (regs) + wave-uniform int
// offset f(kt,half) on SALU -> ~2 VALU per gload.
// C tile = A[M,K] * Bt[.,K]^T ; 512 thr = 8 waves (2Mx4N), BK=64.
// LDS 128KB dynamic: A[2][256][64] @0, B[2][256][64] @32768 (bf16 elems),
// 16B-slot XOR swizzle (slot ^= row&7) via pre-swizzled global source.
// CONV=0: linear A [M][256]. CONV=1: padded NHWC, 3x3 halo shifts, K-order
//   kt = cg*9 + slab (channel-group outer) matching prep's conv-B pack.
// CONV=2: padded NHWC, no shift (plain GEMM over vpad).
// SWZ=0: XCD round-robin (grid 512). SWZ=1: conv one-image per XCD.
// SWZ=2: QKV 1536-block: 3 col-tiles of each row-tile co-resident on one XCD.
// EPI: 0 = qkv-split (q,k -> out[.,512]; v -> vp padded), 1 = f32+bias linear,
//      2 = gelu(+bias) -> bf16 padded.   PERB: Bt += bimg*65536 (per-batch weights).
template <int CONV, int KTOT, int EPI, int PERB, int SWZ>
__global__ __launch_bounds__(512, 1) void mm8(
    const u16* __restrict__ A, const u16* __restrict__ Bt,
    const float* __restrict__ bias, void* __restrict__ out,
    u16* __restrict__ vp) {
  extern __shared__ u16 lds[];
  constexpr int NKT = KTOT / 64;
  constexpr int NITER = NKT / 2;
  const int tid = threadIdx.x;
  const int wave = tid >> 6, lane = tid & 63;
  const int wr = wave >> 2, wcid = wave & 3;
  const int lrow = lane & 15, lk = lane >> 4;
  int bid = (int)blockIdx.x;
  int tile, colbase;
  if (SWZ == 1) {
    const int xcd = bid & 7, k = bid >> 3;
    tile = (xcd + ((k >> 5) << 3)) * 32 + (k & 31);
    colbase = 0;
  } else if (SWZ == 2) {
    const int xcd = bid & 7, s = bid >> 3;
    const int r = s / 3;
    tile = xcd * 64 + r;
    colbase = (s - r * 3) * 256;
  } else {
    tile = (bid & 7) * 64 + (bid >> 3);
    colbase = 0;
  }
  const long rowbase = (long)tile * 256;
  const int bimg = tile >> 6;
  const int y0 = (tile & 63) * 2;
  const u16* BT = PERB ? Bt + (long)bimg * 65536 : Bt;

  // per-lane invariant staging bases
  const int rh0 = tid >> 3;
  const int sg0 = (tid & 7) ^ (rh0 & 7);
  const u16* laneA0 = A + rh0 * 256 + sg0 * 8;
  const u16* laneA1 = laneA0 + 64 * 256;
  const u16* laneB0 = BT + (long)rh0 * KTOT + sg0 * 8;
  const u16* laneB1 = laneB0 + (long)64 * KTOT;
  u16* ldsl = lds + wave * 512;

  auto STAGE = [&](int kt, int isB, int half, int bufq) {
    int uofs;
    if (isB) {
      uofs = (colbase + half * 128) * KTOT + kt * 64;
    } else if (CONV == 1) {
      const int cg = kt / 9;
      const int slab = kt - cg * 9;
      const int ky = slab / 3 - 1, kx = slab - (slab / 3) * 3 - 1;
      uofs = ((bimg * 130 + y0 + half + 1 + ky) * 130 + 1 + kx) * 256 + cg * 64;
    } else if (CONV == 2) {
      uofs = ((bimg * 130 + y0 + half + 1) * 130 + 1) * 256 + kt * 64;
    } else {
      uofs = (int)(rowbase + half * 128) * 256 + kt * 64;
    }
    u16* l = ldsl + (isB ? 32768 : 0) + bufq * 16384 + half * 8192;
    gload16((isB ? laneB0 : laneA0) + uofs, l);
    gload16((isB ? laneB1 : laneA1) + uofs, l + 4096);
  };

  f32x4 acc[8][4] = {};
  bf16x8 bq[4][2];

  // prologue: t0.B0, t0.B1, t0.A0, t0.A1, t1.B0, t1.B1
  STAGE(0, 1, 0, 0); STAGE(0, 1, 1, 0);
  STAGE(0, 0, 0, 0); STAGE(0, 0, 1, 0);
  STAGE(1, 1, 0, 1); STAGE(1, 1, 1, 1);
  asm volatile("s_waitcnt vmcnt(4)" ::: "memory");
  __builtin_amdgcn_s_barrier();
  __builtin_amdgcn_sched_barrier(0);

  for (int it = 0; it < NITER; ++it) {
    const int u0 = 2 * it;
#pragma unroll
    for (int ph = 0; ph < 8; ++ph) {
      constexpr int S_ISB[8]  = {0, 0, 1, 1, 0, 0, 1, 1};
      constexpr int S_HALF[8] = {0, 1, 0, 1, 0, 1, 0, 1};
      constexpr int S_BUF[8]  = {1, 1, 0, 0, 0, 0, 1, 1};
      constexpr int S_DT[8]   = {1, 1, 2, 2, 2, 2, 3, 3};
      const int cbuf = ph >> 2, quad = ph & 3;
      if (quad == 0) {  // B frags once per K-tile (8 ds_read_b128)
#pragma unroll
        for (int nf = 0; nf < 4; ++nf)
#pragma unroll
          for (int ks = 0; ks < 2; ++ks) {
            const int n = wcid * 64 + nf * 16 + lrow;
            const int slot = (ks * 4 + lk) ^ (n & 7);
            bq[nf][ks] = *reinterpret_cast<const bf16x8*>(&lds[32768 + cbuf * 16384 + n * 64 + slot * 8]);
          }
      }
      bf16x8 aq[2][2];
#pragma unroll
      for (int mf = 0; mf < 2; ++mf)
#pragma unroll
        for (int ks = 0; ks < 2; ++ks) {
          const int r = wr * 128 + quad * 32 + mf * 16 + lrow;
          const int slot = (ks * 4 + lk) ^ (r & 7);
          aq[mf][ks] = *reinterpret_cast<const bf16x8*>(&lds[cbuf * 16384 + r * 64 + slot * 8]);
        }
      int st = u0 + S_DT[ph];
      if (st > NKT - 1) st = NKT - 1;  // epilogue dummy stages keep vmcnt counts exact
      STAGE(st, S_ISB[ph], S_HALF[ph], S_BUF[ph]);
      if (quad == 0)
        asm volatile("s_waitcnt lgkmcnt(8)" ::: "memory");  // early partial drain (12 reads issued)
      __builtin_amdgcn_s_barrier();
      asm volatile("s_waitcnt lgkmcnt(0)" ::: "memory");
      __builtin_amdgcn_sched_barrier(0);
      __builtin_amdgcn_s_setprio(1);
#pragma unroll
      for (int mf = 0; mf < 2; ++mf)
#pragma unroll
        for (int nf = 0; nf < 4; ++nf)
#pragma unroll
          for (int ks = 0; ks < 2; ++ks)
            acc[quad * 2 + mf][nf] = __builtin_amdgcn_mfma_f32_16x16x32_bf16(
                aq[mf][ks], bq[nf][ks], acc[quad * 2 + mf][nf], 0, 0, 0);
      __builtin_amdgcn_s_setprio(0);
      __builtin_amdgcn_sched_barrier(0);
      if (quad == 3)
        asm volatile("s_waitcnt vmcnt(4)" ::: "memory");  // counted, never 0
      __builtin_amdgcn_s_barrier();
      __builtin_amdgcn_sched_barrier(0);
    }
  }

  // -------- epilogue (scalar stores; adjacent lanes coalesce) --------
  const int r0 = (lane >> 4) * 4;
  const int occ = lane & 15;
#pragma unroll
  for (int M = 0; M < 8; ++M) {
#pragma unroll
    for (int nf = 0; nf < 4; ++nf) {
      const int col = wcid * 64 + nf * 16 + occ;
#pragma unroll
      for (int i = 0; i < 4; ++i) {
        const int p = wr * 128 + M * 16 + r0 + i;
        float v = acc[M][nf][i];
        if (EPI == 0) {
          const long rowpix = rowbase + p;
          const int gcol = colbase + col;
          if (gcol < 512) {
            reinterpret_cast<u16*>(out)[rowpix * 512 + gcol] = f2bf(v);
          } else {
            const int b = (int)(rowpix >> 14), rem = (int)(rowpix & 16383);
            vp[(((long)b * 130 + (rem >> 7) + 1) * 130 + (rem & 127) + 1) * 256 + (gcol - 512)] = f2bf(v);
          }
        } else if (EPI == 1) {
          reinterpret_cast<float*>(out)[(rowbase + p) * 256 + col] = v + bias[col];
        } else {
          v += bias[col];
          v = 0.5f * v * (1.0f + erff(v * 0.70710678118654752f));
          const int y = y0 + (p >> 7), x = p & 127;
          reinterpret_cast<u16*>(out)[(((long)bimg * 130 + y + 1) * 130 + x + 1) * 256 + col] = f2bf(v);
        }
      }
    }
  }
}

// ---------------- MFMA gram: G[b,h,d,e] = sum_n k[n,d] q[n,e]  (+ col sumsq) ----------------
__global__ __launch_bounds__(256) void gram_mfma(const u16* __restrict__ qkv,
                                                 float* __restrict__ G,
                                                 float* __restrict__ norm2) {
  __shared__ __align__(16) u16 kT[2][32][40];
  __shared__ __align__(16) u16 qT[2][32][40];
  __shared__ float redq[256][4];
  __shared__ float redk[256][4];
  const int nc = blockIdx.x;
  const int bh = blockIdx.y;
  const int b = bh >> 3, h = bh & 7;
  const int t = threadIdx.x;
  const int wave = t >> 6, lane = t & 63;
  const int mh = wave >> 1, nh = wave & 1;
  const int r = t >> 3, cg = (t & 7) * 4;
  const long n0 = (long)b * 16384 + (long)nc * 4096;
  const u16* qp = qkv + n0 * 512 + h * 32;
  const u16* kp = qp + 256;
  f32x4 acc = {0.f, 0.f, 0.f, 0.f};
  float sq[4] = {0, 0, 0, 0}, sk[4] = {0, 0, 0, 0};

  ushort4 pq[4], pk[4];
#pragma unroll
  for (int j = 0; j < 4; ++j) {
    pq[j] = *reinterpret_cast<const ushort4*>(qp + (long)(j * 32 + r) * 512 + cg);
    pk[j] = *reinterpret_cast<const ushort4*>(kp + (long)(j * 32 + r) * 512 + cg);
  }

  for (int s4 = 0; s4 < 32; ++s4) {
#pragma unroll
    for (int c = 0; c < 4; ++c) {
      const int s = s4 * 4 + c;
      const int buf = s & 1;
      kT[buf][cg + 0][r] = pk[c].x; kT[buf][cg + 1][r] = pk[c].y;
      kT[buf][cg + 2][r] = pk[c].z; kT[buf][cg + 3][r] = pk[c].w;
      qT[buf][cg + 0][r] = pq[c].x; qT[buf][cg + 1][r] = pq[c].y;
      qT[buf][cg + 2][r] = pq[c].z; qT[buf][cg + 3][r] = pq[c].w;
      float f;
      f = bf2f(pq[c].x); sq[0] += f * f;
      f = bf2f(pq[c].y); sq[1] += f * f;
      f = bf2f(pq[c].z); sq[2] += f * f;
      f = bf2f(pq[c].w); sq[3] += f * f;
      f = bf2f(pk[c].x); sk[0] += f * f;
      f = bf2f(pk[c].y); sk[1] += f * f;
      f = bf2f(pk[c].z); sk[2] += f * f;
      f = bf2f(pk[c].w); sk[3] += f * f;
      if (s + 4 < 128) {
        pq[c] = *reinterpret_cast<const ushort4*>(qp + (long)((s + 4) * 32 + r) * 512 + cg);
        pk[c] = *reinterpret_cast<const ushort4*>(kp + (long)((s + 4) * 32 + r) * 512 + cg);
      }
      __syncthreads();
      bf16x8 af = *reinterpret_cast<const bf16x8*>(&kT[buf][mh * 16 + (lane & 15)][(lane >> 4) * 8]);
      bf16x8 bf = *reinterpret_cast<const bf16x8*>(&qT[buf][nh * 16 + (lane & 15)][(lane >> 4) * 8]);
      acc = __builtin_amdgcn_mfma_f32_16x16x32_bf16(af, bf, acc, 0, 0, 0);
    }
  }

  float* gp = G + (long)bh * 1024 + (mh * 16 + (lane >> 4) * 4) * 32 + nh * 16 + (lane & 15);
#pragma unroll
  for (int i = 0; i < 4; ++i) atomicAdd(gp + i * 32, acc[i]);

  __syncthreads();
#pragma unroll
  for (int j = 0; j < 4; ++j) { redq[t][j] = sq[j]; redk[t][j] = sk[j]; }
  __syncthreads();
  if (t < 64) {
    const int qk = t >> 5;
    const int colid = t & 31;
    const int cgi = colid >> 2, j = colid & 3;
    float s = 0.f;
#pragma unroll
    for (int r2 = 0; r2 < 32; ++r2)
      s += qk ? redk[r2 * 8 + cgi][j] : redq[r2 * 8 + cgi][j];
    atomicAdd(&norm2[b * 512 + qk * 256 + h * 32 + colid], s);
  }
}

// ---------------- normalize + rescale + softmax over e ----------------
__global__ void attn_softmax(const float* __restrict__ G, const float* __restrict__ norm2,
                             const float* __restrict__ rescale, float* __restrict__ attn) {
  const int bh = blockIdx.x;
  const int b = bh >> 3, h = bh & 7;
  const int t = threadIdx.x;
  __shared__ float iqs[32], iks[32];
  if (t < 32) {
    iqs[t] = 1.0f / fmaxf(sqrtf(norm2[b * 512 + h * 32 + t]), 1e-12f);
    iks[t] = 1.0f / fmaxf(sqrtf(norm2[b * 512 + 256 + h * 32 + t]), 1e-12f);
  }
  __syncthreads();
  if (t < 32) {
    const float rs = rescale[h];
    const float ikd = iks[t] * rs;
    const float* gp = G + ((long)bh * 32 + t) * 32;
    float l[32];
    float mx = -1e30f;
#pragma unroll
    for (int e = 0; e < 32; ++e) {
      l[e] = gp[e] * ikd * iqs[e];
      mx = fmaxf(mx, l[e]);
    }
    float s = 0.f;
#pragma unroll
    for (int e = 0; e < 32; ++e) {
      l[e] = expf(l[e] - mx);
      s += l[e];
    }
    const float inv = 1.0f / s;
    float* op = attn + ((long)bh * 32 + t) * 32;
#pragma unroll
    for (int e = 0; e < 32; ++e) op[e] = l[e] * inv;
  }
}

// ---------------- weff[b][c][h*32+e] = sum_d Wp[c][h*32+d]*attn[b][h][d][e]; + p1pad halo ----------------
__global__ __launch_bounds__(256) void weff_border(const float* __restrict__ Wp,
                                                   const float* __restrict__ attn,
                                                   u16* __restrict__ weff,
                                                   u16* __restrict__ p1pad) {
  const int blk = blockIdx.x;
  const int t = threadIdx.x;
  if (blk < 64) {
    __shared__ float A[32][33];
    const int b = blk >> 3, h = blk & 7;
    const float* ap = attn + (long)blk * 1024;
    for (int j = t; j < 1024; j += 256) A[j >> 5][j & 31] = ap[j];
    __syncthreads();
    const float* wrow = Wp + (long)t * 256 + h * 32;
    float w[32];
#pragma unroll
    for (int d = 0; d < 32; ++d) w[d] = wrow[d];
    u16* orow = weff + ((long)b * 256 + t) * 256 + h * 32;
#pragma unroll
    for (int e = 0; e < 32; ++e) {
      float s = 0.f;
#pragma unroll
      for (int d = 0; d < 32; ++d) s += w[d] * A[d][e];
      orow[e] = f2bf(s);
    }
  } else {
    const int idx = (blk - 64) * 256 + t;
    if (idx < 8 * 516 * 32) border_body(p1pad, idx);
  }
}

// ---------------- launch ----------------
extern "C" void kernel_launch(void* const* d_in, const int* in_sizes, int n_in,
                              void* d_out, int out_size, void* d_ws, size_t ws_size,
                              hipStream_t stream) {
  const float* x = (const float*)d_in[0];
  const float* Wq = (const float*)d_in[1];
  const float* Wk = (const float*)d_in[2];
  const float* Wv = (const float*)d_in[3];
  const float* resc = (const float*)d_in[4];
  const float* Wp = (const float*)d_in[5];
  const float* bp = (const float*)d_in[6];
  const float* Wc1 = (const float*)d_in[7];
  const float* bc1 = (const float*)d_in[8];
  const float* Wc2 = (const float*)d_in[9];
  const float* bc2 = (const float*)d_in[10];

  char* ws = (char*)d_ws;
  u16* qkv   = (u16*)(ws + 0L);            // [131072][512] q|k ; dead after gram
  u16* p1pad = (u16*)(ws + 0L);            // [8][130][130][256] conv1 out (overlays qkv)
  u16* vpad  = (u16*)(ws + 134217728L);    // [8][130][130][256] v padded
  u16* xb    = (u16*)(ws + 203440128L);    // x bf16
  u16* wqkv  = (u16*)(ws + 270548992L);    // [768][256]
  u16* wc1r  = (u16*)(ws + 270942208L);    // [256][2304]
  u16* wc2r  = (u16*)(ws + 272121856L);    // [256][2304]
  u16* weff  = (u16*)(ws + 273301504L);    // [8][256][256]
  float* norm2 = (float*)(ws + 274350080L);  // [8][512]
  float* G     = (float*)(ws + 274366464L);  // [64][32][32]
  float* attn  = (float*)(ws + 274628608L);  // [64][32][32]

  float* out_c = (float*)d_out;
  float* out_p = out_c + 33554432L;

  hipMemsetAsync(norm2, 0, 16384 + 262144, stream);

  // fused prep: x cvt + weight cvts + conv-weight packs + vpad halo
  prep<<<6972, 256, 0, stream>>>(x, xb, Wq, Wk, Wv, Wc1, Wc2, wqkv, wc1r, wc2r, vpad);

  // QKV projection: q,k -> qkv[131072][512]; v -> vpad (1536 blocks, co-XCD col-tiles)
  mm8<0, 256, 0, 0, 2><<<1536, 512, 131072, stream>>>(xb, wqkv, nullptr, qkv, vpad);

  gram_mfma<<<dim3(4, 64), 256, 0, stream>>>(qkv, G, norm2);
  attn_softmax<<<64, 64, 0, stream>>>(G, norm2, resc, attn);
  weff_border<<<580, 256, 0, stream>>>(Wp, attn, weff, p1pad);

  // out_c = v @ weff[b]^T + bp   (reads vpad directly)
  mm8<2, 256, 1, 1, 0><<<512, 512, 131072, stream>>>(vpad, weff, bp, out_c, nullptr);

  // conv branch (cgroup-outer K-order for L2 locality)
  mm8<1, 2304, 2, 0, 1><<<512, 512, 131072, stream>>>(vpad, wc1r, bc1, p1pad, nullptr);
  mm8<1, 2304, 1, 0, 1><<<512, 512, 131072, stream>>>(p1pad, wc2r, bc2, out_p, nullptr);
}